// Round 7
// baseline (55.080 us; speedup 1.0000x reference)
//
#include <hip/hip_runtime.h>
#include <math.h>

#define EPS_COS 1e-8f
#define EPS_ADD 1e-12f

typedef float f4 __attribute__((ext_vector_type(4)));

// One block per batch (grid = B = 256 = #CUs), 1024 threads = 16 waves.
// Streaming pass: each wave reads a contiguous 4 KiB slice per round
// (16 rows x 256 B); chunk u covers a contiguous 1 KiB (f4 idx = wave*256 +
// u*64 + lane -> row = wave*16 + u*4 + (lane>>4), col = lane&15).
// R7 deltas vs R6 (54.0us):
//   * 16-deep prefetch: 4 named f4[4] buffers = 16 KiB in flight per wave
//     (~256 KiB/CU) -- tests the outstanding-read-limit theory.
//   * __builtin_nontemporal_load on mem -- read-once stream, skip L2/L3
//     allocation.
// Row reduction via DPP row_shl adds into lane 0. Scores |t| < 1 so exp needs
// no max subtract; softmax denominator accumulated inline.
// Assumes N == 4096 (nIter = 16 divisible by 4), M == 64.

constexpr int NTHREADS = 1024;
constexpr int NWAVES   = NTHREADS / 64;   // 16
constexpr int MAX_N    = 4096;

// Sum over each 16-lane row; result valid in lane 0 of each 16-lane group.
__device__ __forceinline__ float row_sum16_lane0(float x) {
    int t;
    t = __builtin_amdgcn_update_dpp(0, __float_as_int(x), 0x108, 0xf, 0xf, true); // row_shl:8
    x += __int_as_float(t);
    t = __builtin_amdgcn_update_dpp(0, __float_as_int(x), 0x104, 0xf, 0xf, true); // row_shl:4
    x += __int_as_float(t);
    t = __builtin_amdgcn_update_dpp(0, __float_as_int(x), 0x102, 0xf, 0xf, true); // row_shl:2
    x += __int_as_float(t);
    t = __builtin_amdgcn_update_dpp(0, __float_as_int(x), 0x101, 0xf, 0xf, true); // row_shl:1
    x += __int_as_float(t);
    return x;
}

__global__ __launch_bounds__(NTHREADS, 1) void ntm_fused_kernel(
    const float* __restrict__ beta,    // [B,1]
    const float* __restrict__ kappa,   // [B,64]
    const float* __restrict__ gamma,   // [B,1]
    const float* __restrict__ g,       // [B,1]
    const float* __restrict__ s,       // [B,S]
    const float* __restrict__ w_prev,  // [B,N]
    const float* __restrict__ mem,     // [B,N,64]
    float* __restrict__ out,           // [B,N]
    int N, int S)
{
    const int b    = blockIdx.x;
    const int tid  = threadIdx.x;
    const int lane = tid & 63;
    const int wave = tid >> 6;
    const int l16  = lane & 15;
    const int rg   = lane >> 4;          // row within a 4-row chunk

    __shared__ float sh[MAX_N];          // e values -> interpolated weights
    __shared__ float red[NWAVES];

    // ---- prefetch w_prev into registers (overlaps the whole stream) ----
    const f4 wp_reg = reinterpret_cast<const f4*>(w_prev + (size_t)b * N)[tid];

    // ---- kappa fragment + norm ----
    f4 kv = reinterpret_cast<const f4*>(kappa + (size_t)b * 64)[l16];
    kv += (f4)EPS_ADD;
    float nb2 = kv.x * kv.x + kv.y * kv.y + kv.z * kv.z + kv.w * kv.w;
    nb2 = row_sum16_lane0(nb2);
    nb2 = __shfl(nb2, (lane >> 4) << 4);     // broadcast lane-0 sum to the group
    const float bscale = beta[b] / fmaxf(sqrtf(nb2), EPS_COS);

    // ---- streaming pass: 256 rows/round (16 waves x 16 rows) ----
    const int nIter = N >> 8;            // 16 for N=4096 (divisible by 4)
    const int rowb  = wave * 16 + rg;    // + u*4 + it*256
    const f4* p = reinterpret_cast<const f4*>(mem + (size_t)b * N * 64)
                  + (size_t)wave * 256 + lane;
    // round stride = 4096 f4 (256 rows); chunk stride = 64 f4 (1 KiB)

    float lsum = 0.0f;
    f4 aA[4], aB[4], aC[4], aD[4];
#pragma unroll
    for (int u = 0; u < 4; ++u) aA[u] = __builtin_nontemporal_load(p + u * 64);
#pragma unroll
    for (int u = 0; u < 4; ++u) aB[u] = __builtin_nontemporal_load(p + 4096 + u * 64);
#pragma unroll
    for (int u = 0; u < 4; ++u) aC[u] = __builtin_nontemporal_load(p + 8192 + u * 64);
#pragma unroll
    for (int u = 0; u < 4; ++u) aD[u] = __builtin_nontemporal_load(p + 12288 + u * 64);

#define NTM_BODY(BUF, IT_OFF)                                                   \
    {                                                                           \
        f4 c[4];                                                                \
        _Pragma("unroll")                                                       \
        for (int u = 0; u < 4; ++u) c[u] = BUF[u];                              \
        if (it + (IT_OFF) + 4 < nIter) {                                        \
            const f4* pn = p + (size_t)(it + (IT_OFF) + 4) * 4096;              \
            _Pragma("unroll")                                                   \
            for (int u = 0; u < 4; ++u)                                         \
                BUF[u] = __builtin_nontemporal_load(pn + u * 64);               \
        }                                                                       \
        _Pragma("unroll")                                                       \
        for (int u = 0; u < 4; ++u) {                                           \
            const f4 v = c[u];                                                  \
            float d  = v.x * kv.x + v.y * kv.y + v.z * kv.z + v.w * kv.w;       \
            float n2 = v.x * v.x + v.y * v.y + v.z * v.z + v.w * v.w;           \
            d  = row_sum16_lane0(d);                                            \
            n2 = row_sum16_lane0(n2);                                           \
            if (l16 == 0) {                                                     \
                const float t = bscale * d * rsqrtf(fmaxf(n2, 1e-16f));         \
                const float e = expf(t);                                        \
                sh[rowb + u * 4 + (it + (IT_OFF)) * 256] = e;                    \
                lsum += e;                                                      \
            }                                                                   \
        }                                                                       \
    }

    for (int it = 0; it < nIter; it += 4) {
        NTM_BODY(aA, 0)
        NTM_BODY(aB, 1)
        NTM_BODY(aC, 2)
        NTM_BODY(aD, 3)
    }
#undef NTM_BODY

    // ---- block reduce: softmax denominator ----
#pragma unroll
    for (int m = 1; m < 64; m <<= 1) lsum += __shfl_xor(lsum, m);
    if (lane == 0) red[wave] = lsum;
    __syncthreads();                      // also covers all sh[] writes
    float tot = 0.0f;
#pragma unroll
    for (int i = 0; i < NWAVES; ++i) tot += red[i];

    // ---- interpolate in place (one f4 per thread) ----
    const float gv = g[b];
    const float ws = gv / tot;            // g * (e / tot)
    f4* sh4 = reinterpret_cast<f4*>(sh);
    {
        const f4 ev = sh4[tid];
        sh4[tid] = ws * ev + (1.0f - gv) * wp_reg;
    }
    __syncthreads();

    // ---- circular shift + sharpen (results stay in registers) ----
    const float gam = gamma[b];
    float sv[8];
    const int Sc = (S < 8) ? S : 8;
    for (int j = 0; j < Sc; ++j) sv[j] = s[(size_t)b * S + j];

    const int i0 = tid * 4;
    const int mask = N - 1;               // N is a power of two
    float o[4];
    float ssum = 0.0f;
#pragma unroll
    for (int k = 0; k < 4; ++k) {
        float wh = 0.0f;
        for (int j = 0; j < Sc; ++j) {
            const int idx = (i0 + k + j - 1) & mask;
            wh += sv[j] * sh[idx];
        }
        o[k] = powf(wh, gam);
        ssum += o[k];
    }

    // ---- block reduce: sharpen denominator ----
#pragma unroll
    for (int m = 1; m < 64; m <<= 1) ssum += __shfl_xor(ssum, m);
    if (lane == 0) red[wave] = ssum;
    __syncthreads();
    float stot = 0.0f;
#pragma unroll
    for (int i = 0; i < NWAVES; ++i) stot += red[i];

    // ---- normalize + vector store ----
    const float inv_den = 1.0f / (stot + EPS_ADD);
    f4 ov;
    ov.x = o[0] * inv_den; ov.y = o[1] * inv_den;
    ov.z = o[2] * inv_den; ov.w = o[3] * inv_den;
    reinterpret_cast<f4*>(out + (size_t)b * N)[tid] = ov;
}

extern "C" void kernel_launch(void* const* d_in, const int* in_sizes, int n_in,
                              void* d_out, int out_size, void* d_ws, size_t ws_size,
                              hipStream_t stream) {
    const float* beta   = (const float*)d_in[0];
    const float* kappa  = (const float*)d_in[1];
    const float* gamma  = (const float*)d_in[2];
    const float* g      = (const float*)d_in[3];
    const float* s      = (const float*)d_in[4];
    const float* w_prev = (const float*)d_in[5];
    const float* mem    = (const float*)d_in[6];
    float* out          = (float*)d_out;

    const int B = in_sizes[0];            // beta is (B,1)
    const int N = in_sizes[5] / B;        // w_prev is (B,N)
    const int S = in_sizes[4] / B;        // s is (B,S)

    ntm_fused_kernel<<<B, NTHREADS, 0, stream>>>(
        beta, kappa, gamma, g, s, w_prev, mem, out, N, S);
}